// Round 1
// 658.796 us; speedup vs baseline: 1.2145x; 1.2145x over previous
//
#include <hip/hip_runtime.h>

// Problem constants
#define B_     4
#define T_     400
#define U_     64
#define E_     320
#define INNER_ 512
#define VOCAB_ 1024
#define M_     (B_ * T_ * U_)        // 102400
#define BT_    (B_ * T_)             // 1600
#define NROWS_ (BT_ + B_ * U_)       // 1856 projection rows

typedef __attribute__((ext_vector_type(8))) short short8;
typedef __attribute__((ext_vector_type(4))) float f32x4;

__device__ __forceinline__ unsigned short f2bf(float f) {
    union { float f; unsigned u; } v;
    v.f = f;
    unsigned u = v.u;
    u += 0x7fffu + ((u >> 16) & 1u);   // round-to-nearest-even
    return (unsigned short)(u >> 16);
}

__device__ __forceinline__ float tanh_fast(float x) {
    // tanh(x) = 1 - 2/(exp(2x)+1); exp overflow/underflow saturate correctly.
    float e = __expf(2.0f * x);
    return 1.0f - 2.0f / (e + 1.0f);
}

// Async global->LDS, 16B per lane. LDS dest must be wave-uniform base;
// HW writes base + lane*16 (m104). Global src IS per-lane.
__device__ __forceinline__ void gload_lds16(const void* g, void* l) {
    __builtin_amdgcn_global_load_lds(
        (const __attribute__((address_space(1))) unsigned int*)g,
        (__attribute__((address_space(3))) unsigned int*)l,
        16, 0, 0);
}

// ---------------------------------------------------------------------------
// Kernel 1 (fused prep): blocks [0,232) = projection (b1 folded into dec
// rows), blocks [232,488) = W2 fp32->bf16 conversion.
// ---------------------------------------------------------------------------
#define PROJ_BLOCKS 232
#define CVT_BLOCKS  256

__global__ __launch_bounds__(256) void prep_kernel(
    const float* __restrict__ enc,
    const float* __restrict__ dec,
    const float* __restrict__ W1,
    const float* __restrict__ b1,
    const float* __restrict__ W2,
    float* __restrict__ proj,
    unsigned short* __restrict__ W2bf) {
    __shared__ float xs[8][E_];   // 10240 B
    const int tid = threadIdx.x;

    if (blockIdx.x >= PROJ_BLOCKS) {
        // ---- W2 conversion ----
        const int i = ((blockIdx.x - PROJ_BLOCKS) * 256 + tid) * 8;
        float4 a = *(const float4*)(W2 + i);
        float4 b = *(const float4*)(W2 + i + 4);
        short8 o;
        o[0] = (short)f2bf(a.x); o[1] = (short)f2bf(a.y);
        o[2] = (short)f2bf(a.z); o[3] = (short)f2bf(a.w);
        o[4] = (short)f2bf(b.x); o[5] = (short)f2bf(b.y);
        o[6] = (short)f2bf(b.z); o[7] = (short)f2bf(b.w);
        *(short8*)(W2bf + i) = o;
        return;
    }

    // ---- projection: 8 rows per block ----
    const int r0 = blockIdx.x * 8;
    for (int i = tid; i < 8 * E_; i += 256) {
        const int rr = i / E_;
        const int cc = i - rr * E_;
        const int row = r0 + rr;
        const float* src = (row < BT_) ? (enc + row * E_)
                                       : (dec + (row - BT_) * E_);
        xs[rr][cc] = src[cc];
    }
    const int colbase = (r0 < BT_) ? 0 : E_;
    __syncthreads();

    for (int o = tid; o < INNER_; o += 256) {   // 2 iterations
        const float* w = W1 + o * (2 * E_) + colbase;
        float acc[8] = {};
        for (int c = 0; c < E_; c += 4) {
            float4 wv = *(const float4*)(w + c);
            #pragma unroll
            for (int rr = 0; rr < 8; ++rr) {
                float4 x = *(const float4*)(&xs[rr][c]);
                acc[rr] += wv.x * x.x + wv.y * x.y + wv.z * x.z + wv.w * x.w;
            }
        }
        // fold b1 into the dec rows so h = tanh(encp + decp) downstream
        const float badd = colbase ? b1[o] : 0.0f;
        #pragma unroll
        for (int rr = 0; rr < 8; ++rr)
            proj[(r0 + rr) * INNER_ + o] = acc[rr] + badd;
    }
}

// ---------------------------------------------------------------------------
// Kernel 2: h = tanh(encp[bt] + decp[b,u]) -> bf16 (102400 x 512), computed
// ONCE (vs 8x recompute in the old fused joint). Write-BW bound (~105 MB).
// One wave covers one full row (64 lanes x 8 elems = 512).
// ---------------------------------------------------------------------------
__global__ __launch_bounds__(256) void hgen_kernel(
    const float* __restrict__ encp,
    const float* __restrict__ decp,
    unsigned short* __restrict__ hbf) {
    const int gid = blockIdx.x * 256 + threadIdx.x;
    const int r   = gid >> 6;           // output row 0..102399
    const int kk  = (gid & 63) << 3;    // k offset, 8 elems/thread
    const int bt  = r >> 6;             // b*T + t
    const int u   = r & 63;
    const int b   = bt / T_;
    const float* e = encp + bt * INNER_ + kk;
    const float* d = decp + (b * U_ + u) * INNER_ + kk;
    short8 o;
    #pragma unroll
    for (int i = 0; i < 2; ++i) {
        float4 e4 = *(const float4*)(e + i * 4);
        float4 d4 = *(const float4*)(d + i * 4);
        o[i * 4 + 0] = (short)f2bf(tanh_fast(e4.x + d4.x));
        o[i * 4 + 1] = (short)f2bf(tanh_fast(e4.y + d4.y));
        o[i * 4 + 2] = (short)f2bf(tanh_fast(e4.z + d4.z));
        o[i * 4 + 3] = (short)f2bf(tanh_fast(e4.w + d4.w));
    }
    *(short8*)(hbf + ((size_t)r << 9) + kk) = o;
}

// ---------------------------------------------------------------------------
// Kernel 3: pure bf16 GEMM (m97 structure): C(102400x1024) = h @ W2bf^T + b2.
// 128x128 tile, BK=32, linear LDS + global_load_lds dwordx4 staging,
// 4 waves 2x2, each wave 64x64 via 4x4 grid of 16x16x32 bf16 MFMAs.
// ---------------------------------------------------------------------------
#define JBM 128
#define JBN 128
#define JBK 32

__global__ __launch_bounds__(256) void joint_gemm_kernel(
    const unsigned short* __restrict__ hbf,
    const unsigned short* __restrict__ W2bf,
    const float* __restrict__ b2,
    float* __restrict__ out) {
    __shared__ unsigned short As[JBM * JBK];   // 8 KiB, linear (no pad)
    __shared__ unsigned short Bs[JBN * JBK];   // 8 KiB

    // XCD swizzle: 8 N-tiles of one M-tile land on one XCD (block i -> XCD i%8)
    const int bid = blockIdx.x;
    const int c  = bid & 7;
    const int j  = bid >> 3;
    const int mt = (j & ~7) | c;
    const int nt = j & 7;
    const int m0 = mt * JBM;
    const int n0 = nt * JBN;

    const int tid  = threadIdx.x;
    const int wid  = tid >> 6;
    const int lane = tid & 63;
    const int wm   = (wid & 1) * 64;
    const int wn   = (wid >> 1) * 64;

    const int fr   = lane & 15;
    const int koff = (lane >> 4) * 8;   // bf16 elems within the 32-wide k row

    f32x4 acc[4][4] = {};

    const char* hbase = (const char*)hbf;
    const char* wbase = (const char*)W2bf;

    for (int kt = 0; kt < INNER_; kt += JBK) {   // 16 iterations
        const int kb = kt * 2;   // byte offset of k-tile within a 1024B row
        // ---- stage: 8192 B per tile = 2 calls x 4 waves x 1024 B ----
        #pragma unroll
        for (int c2 = 0; c2 < 2; ++c2) {
            const int p    = c2 * 4096 + tid * 16;       // per-lane byte in tile
            const int r    = p >> 6;                     // tile row (64 B rows)
            const int off  = p & 63;                     // byte within k row
            const int ldsb = c2 * 4096 + (wid << 10);    // wave-uniform dest
            gload_lds16(hbase + (((size_t)(m0 + r)) << 10) + kb + off,
                        (char*)As + ldsb);
            gload_lds16(wbase + (((size_t)(n0 + r)) << 10) + kb + off,
                        (char*)Bs + ldsb);
        }
        __syncthreads();   // compiler drains vmcnt before s_barrier

        // ---- fragments + MFMA ----
        short8 af[4], bfr[4];
        #pragma unroll
        for (int i = 0; i < 4; ++i)
            af[i] = *(const short8*)(As + (wm + fr + i * 16) * JBK + koff);
        #pragma unroll
        for (int i = 0; i < 4; ++i)
            bfr[i] = *(const short8*)(Bs + (wn + fr + i * 16) * JBK + koff);
        #pragma unroll
        for (int im = 0; im < 4; ++im)
            #pragma unroll
            for (int in = 0; in < 4; ++in)
                acc[im][in] = __builtin_amdgcn_mfma_f32_16x16x32_bf16(
                    af[im], bfr[in], acc[im][in], 0, 0, 0);

        __syncthreads();
    }

    // ---- epilogue: + b2, fp32 store. C layout: col=lane&15,
    // row=(lane>>4)*4+reg (m89-verified) ----
    const int rq = (lane >> 4) * 4;
    const int cl = lane & 15;
    #pragma unroll
    for (int in = 0; in < 4; ++in) {
        const int col = n0 + wn + in * 16 + cl;
        const float bias = b2[col];
        #pragma unroll
        for (int im = 0; im < 4; ++im) {
            const size_t rbase = (size_t)(m0 + wm + im * 16 + rq);
            #pragma unroll
            for (int r = 0; r < 4; ++r) {
                out[(rbase + r) * VOCAB_ + col] = acc[im][in][r] + bias;
            }
        }
    }
}

// ---------------------------------------------------------------------------
// Fallback (old fused joint, h on the fly) — used only if ws too small for h.
// b1 is folded into decp by prep_kernel, so no b1 here.
// ---------------------------------------------------------------------------
#define BM  128
#define BN  128
#define BK  32
#define LDA 40

__global__ __launch_bounds__(256) void joint_fb_kernel(
    const float* __restrict__ encp,
    const float* __restrict__ decp,
    const unsigned short* __restrict__ W2bf,
    const float* __restrict__ b2,
    float* __restrict__ out) {
    __shared__ unsigned short As[BM * LDA];
    __shared__ unsigned short Bs[BN * LDA];

    const int bid = blockIdx.x;
    const int c  = bid & 7;
    const int j  = bid >> 3;
    const int mt = (j & ~7) | c;
    const int nt = j & 7;
    const int m0 = mt * BM;
    const int n0 = nt * BN;

    const int tid  = threadIdx.x;
    const int wid  = tid >> 6;
    const int lane = tid & 63;
    const int wm   = (wid & 1) * 64;
    const int wn   = (wid >> 1) * 64;

    const int sr = tid >> 1;
    const int sk = (tid & 1) * 16;
    const int gr = m0 + sr;
    const int bt = gr >> 6;
    const int uu = gr & 63;
    const int bb = bt / T_;
    const float* eprow = encp + bt * INNER_;
    const float* dprow = decp + (bb * U_ + uu) * INNER_;
    const unsigned short* wrow = W2bf + (size_t)(n0 + sr) * INNER_;

    f32x4 acc[4][4] = {};

    for (int kt = 0; kt < INNER_; kt += BK) {
        const float* ep = eprow + kt + sk;
        const float* dp = dprow + kt + sk;
        short8 p0, p1;
        #pragma unroll
        for (int i = 0; i < 4; ++i) {
            float4 e4 = *(const float4*)(ep + i * 4);
            float4 d4 = *(const float4*)(dp + i * 4);
            unsigned short h0 = f2bf(tanh_fast(e4.x + d4.x));
            unsigned short h1 = f2bf(tanh_fast(e4.y + d4.y));
            unsigned short h2 = f2bf(tanh_fast(e4.z + d4.z));
            unsigned short h3 = f2bf(tanh_fast(e4.w + d4.w));
            if (i < 2) {
                p0[i * 4 + 0] = (short)h0; p0[i * 4 + 1] = (short)h1;
                p0[i * 4 + 2] = (short)h2; p0[i * 4 + 3] = (short)h3;
            } else {
                p1[(i - 2) * 4 + 0] = (short)h0; p1[(i - 2) * 4 + 1] = (short)h1;
                p1[(i - 2) * 4 + 2] = (short)h2; p1[(i - 2) * 4 + 3] = (short)h3;
            }
        }
        *(short8*)(As + sr * LDA + sk)     = p0;
        *(short8*)(As + sr * LDA + sk + 8) = p1;

        short8 w0 = *(const short8*)(wrow + kt + sk);
        short8 w1 = *(const short8*)(wrow + kt + sk + 8);
        *(short8*)(Bs + sr * LDA + sk)     = w0;
        *(short8*)(Bs + sr * LDA + sk + 8) = w1;

        __syncthreads();

        const int fr   = lane & 15;
        const int koff = (lane >> 4) * 8;
        short8 af[4], bfr[4];
        #pragma unroll
        for (int i = 0; i < 4; ++i)
            af[i] = *(const short8*)(As + (wm + fr + i * 16) * LDA + koff);
        #pragma unroll
        for (int i = 0; i < 4; ++i)
            bfr[i] = *(const short8*)(Bs + (wn + fr + i * 16) * LDA + koff);
        #pragma unroll
        for (int im = 0; im < 4; ++im)
            #pragma unroll
            for (int in = 0; in < 4; ++in)
                acc[im][in] = __builtin_amdgcn_mfma_f32_16x16x32_bf16(
                    af[im], bfr[in], acc[im][in], 0, 0, 0);

        __syncthreads();
    }

    const int rq = (lane >> 4) * 4;
    const int cl = lane & 15;
    #pragma unroll
    for (int in = 0; in < 4; ++in) {
        const int col = n0 + wn + in * 16 + cl;
        const float bias = b2[col];
        #pragma unroll
        for (int im = 0; im < 4; ++im) {
            const size_t rbase = (size_t)(m0 + wm + im * 16 + rq);
            #pragma unroll
            for (int r = 0; r < 4; ++r) {
                out[(rbase + r) * VOCAB_ + col] = acc[im][in][r] + bias;
            }
        }
    }
}

extern "C" void kernel_launch(void* const* d_in, const int* in_sizes, int n_in,
                              void* d_out, int out_size, void* d_ws, size_t ws_size,
                              hipStream_t stream) {
    const float* enc = (const float*)d_in[0];  // (4,400,320) fp32
    const float* dec = (const float*)d_in[1];  // (4,64,320)  fp32
    const float* W1  = (const float*)d_in[2];  // (512,640)   fp32
    const float* b1  = (const float*)d_in[3];  // (512,)      fp32
    const float* W2  = (const float*)d_in[4];  // (1024,512)  fp32
    const float* b2  = (const float*)d_in[5];  // (1024,)     fp32
    float* out = (float*)d_out;                // (4,400,64,1024) fp32

    // ws layout: proj fp32 (1856x512), W2bf (1 MiB), hbf (102400x512 bf16)
    const size_t PROJ_BYTES = (size_t)NROWS_ * INNER_ * sizeof(float);   // 3,801,088
    const size_t W2_BYTES   = (size_t)VOCAB_ * INNER_ * 2;               // 1,048,576
    const size_t H_BYTES    = (size_t)M_ * INNER_ * 2;                   // 104,857,600

    float* proj = (float*)d_ws;
    float* encp = proj;                                // rows 0..1599
    float* decp = proj + (size_t)BT_ * INNER_;         // rows 1600..1855 (b1 folded)
    unsigned short* W2bf = (unsigned short*)((char*)d_ws + PROJ_BYTES);
    unsigned short* hbf  = (unsigned short*)((char*)d_ws + PROJ_BYTES + W2_BYTES);

    prep_kernel<<<PROJ_BLOCKS + CVT_BLOCKS, 256, 0, stream>>>(
        enc, dec, W1, b1, W2, proj, W2bf);

    const int grid = (M_ / JBM) * (VOCAB_ / JBN);  // 6400

    if (ws_size >= PROJ_BYTES + W2_BYTES + H_BYTES) {
        hgen_kernel<<<(M_ * INNER_) / (8 * 256), 256, 0, stream>>>(encp, decp, hbf);
        joint_gemm_kernel<<<grid, 256, 0, stream>>>(hbf, W2bf, b2, out);
    } else {
        joint_fb_kernel<<<grid, 256, 0, stream>>>(encp, decp, W2bf, b2, out);
    }
}

// Round 3
// 615.057 us; speedup vs baseline: 1.3008x; 1.0711x over previous
//
#include <hip/hip_runtime.h>

// Problem constants
#define B_     4
#define T_     400
#define U_     64
#define E_     320
#define INNER_ 512
#define VOCAB_ 1024
#define M_     (B_ * T_ * U_)        // 102400
#define BT_    (B_ * T_)             // 1600
#define NROWS_ (BT_ + B_ * U_)       // 1856 projection rows

#define MT_    (M_ / 256)            // 400 M-tiles of 256 rows
#define NT_    (VOCAB_ / 256)        // 4 N-tiles of 256 cols
#define KT_    (INNER_ / 64)         // 8 K-tiles of 64

typedef __attribute__((ext_vector_type(8))) short short8;
typedef __attribute__((ext_vector_type(4))) float f32x4;

__device__ __forceinline__ unsigned short f2bf(float f) {
    union { float f; unsigned u; } v;
    v.f = f;
    unsigned u = v.u;
    u += 0x7fffu + ((u >> 16) & 1u);   // round-to-nearest-even
    return (unsigned short)(u >> 16);
}

__device__ __forceinline__ float tanh_fast(float x) {
    float e = __expf(2.0f * x);
    return 1.0f - 2.0f / (e + 1.0f);
}

// Async global->LDS, 16B/lane. LDS dest = wave-uniform base (+lane*16 by HW);
// global src is per-lane (m104).
__device__ __forceinline__ void gload_lds16(const void* g, void* l) {
    __builtin_amdgcn_global_load_lds(
        (const __attribute__((address_space(1))) unsigned int*)g,
        (__attribute__((address_space(3))) unsigned int*)l,
        16, 0, 0);
}

// Pre-swizzled tile-image byte offset for (row r in 0..255, elem-byte eb=2*elem,
// eb a multiple of 16). XOR of bits 4-6 with row&7: ds_read_b128 of a column
// slice becomes 2-way bank aliasing (free, m136) instead of 16/32-way.
__device__ __forceinline__ int img_off(int r, int eb) {
    return r * 128 + (eb ^ ((r & 7) << 4));
}

// ---------------------------------------------------------------------------
// Kernel 1 (fused prep): blocks [0,232) projection (b1 folded into dec rows),
// blocks [232,488) = W2 fp32->bf16 into the swizzled (kt,nt) tile image.
// ---------------------------------------------------------------------------
#define PROJ_BLOCKS 232
#define CVT_BLOCKS  256

__global__ __launch_bounds__(256) void prep_kernel(
    const float* __restrict__ enc,
    const float* __restrict__ dec,
    const float* __restrict__ W1,
    const float* __restrict__ b1,
    const float* __restrict__ W2,
    float* __restrict__ proj,
    char* __restrict__ w2t) {
    __shared__ float xs[8][E_];
    const int tid = threadIdx.x;

    if (blockIdx.x >= PROJ_BLOCKS) {
        // ---- W2 conversion into tiled+swizzled image ----
        const int gid = (blockIdx.x - PROJ_BLOCKS) * 256 + tid;
        const int v  = gid >> 6;           // vocab row 0..1023
        const int kk = (gid & 63) * 8;     // k elem 0..504
        float4 a = *(const float4*)(W2 + v * INNER_ + kk);
        float4 b = *(const float4*)(W2 + v * INNER_ + kk + 4);
        short8 o;
        o[0] = (short)f2bf(a.x); o[1] = (short)f2bf(a.y);
        o[2] = (short)f2bf(a.z); o[3] = (short)f2bf(a.w);
        o[4] = (short)f2bf(b.x); o[5] = (short)f2bf(b.y);
        o[6] = (short)f2bf(b.z); o[7] = (short)f2bf(b.w);
        const int kt = kk >> 6, e0 = kk & 63, nt = v >> 8, vl = v & 255;
        *(short8*)(w2t + (((size_t)(kt * NT_ + nt)) << 15) + img_off(vl, e0 * 2)) = o;
        return;
    }

    // ---- projection: 8 rows per block ----
    const int r0 = blockIdx.x * 8;
    for (int i = tid; i < 8 * E_; i += 256) {
        const int rr = i / E_;
        const int cc = i - rr * E_;
        const int row = r0 + rr;
        const float* src = (row < BT_) ? (enc + row * E_)
                                       : (dec + (row - BT_) * E_);
        xs[rr][cc] = src[cc];
    }
    const int colbase = (r0 < BT_) ? 0 : E_;
    __syncthreads();

    for (int o = tid; o < INNER_; o += 256) {
        const float* w = W1 + o * (2 * E_) + colbase;
        float acc[8] = {};
        for (int c = 0; c < E_; c += 4) {
            float4 wv = *(const float4*)(w + c);
            #pragma unroll
            for (int rr = 0; rr < 8; ++rr) {
                float4 x = *(const float4*)(&xs[rr][c]);
                acc[rr] += wv.x * x.x + wv.y * x.y + wv.z * x.z + wv.w * x.w;
            }
        }
        const float badd = colbase ? b1[o] : 0.0f;
        #pragma unroll
        for (int rr = 0; rr < 8; ++rr)
            proj[(r0 + rr) * INNER_ + o] = acc[rr] + badd;
    }
}

// ---------------------------------------------------------------------------
// Kernel 2: h = tanh(encp + decp) -> bf16 into tiled+swizzled (kt,mt) image.
// ---------------------------------------------------------------------------
__global__ __launch_bounds__(256) void hgen_kernel(
    const float* __restrict__ encp,
    const float* __restrict__ decp,
    char* __restrict__ hbf) {
    const int gid = blockIdx.x * 256 + threadIdx.x;
    const int r   = gid >> 6;           // output row 0..102399
    const int kk  = (gid & 63) << 3;    // k offset, 8 elems/thread
    const int bt  = r >> 6;
    const int u   = r & 63;
    const int b   = bt / T_;
    const float* e = encp + bt * INNER_ + kk;
    const float* d = decp + (b * U_ + u) * INNER_ + kk;
    short8 o;
    #pragma unroll
    for (int i = 0; i < 2; ++i) {
        float4 e4 = *(const float4*)(e + i * 4);
        float4 d4 = *(const float4*)(d + i * 4);
        o[i * 4 + 0] = (short)f2bf(tanh_fast(e4.x + d4.x));
        o[i * 4 + 1] = (short)f2bf(tanh_fast(e4.y + d4.y));
        o[i * 4 + 2] = (short)f2bf(tanh_fast(e4.z + d4.z));
        o[i * 4 + 3] = (short)f2bf(tanh_fast(e4.w + d4.w));
    }
    const int kt = kk >> 6, e0 = kk & 63, mt = r >> 8, rl = r & 255;
    *(short8*)(hbf + (((size_t)(kt * MT_ + mt)) << 15) + img_off(rl, e0 * 2)) = o;
}

// ---------------------------------------------------------------------------
// Kernel 3: 256x256 / BK=64 / 8-wave (2Mx4N) 8-phase GEMM with counted vmcnt.
// K=512 -> 8 K-tiles, 4 regions each (RA0,RB0,RB1,RA1 = 16KB), 32 phases.
// Region rho issues at phase rho-5; vmcnt(6)+barrier at phase g guarantees
// regions issued <= g+1 have landed for ALL waves. LDS double-buffered by
// K-tile parity (2 x 64KB = 128KB, STATIC shared — no hipFuncSetAttribute,
// which is a host API call inside kernel_launch -> graph-capture tripwire).
// Frags read once per tile (held in regs across phases).
// ---------------------------------------------------------------------------
__global__ __launch_bounds__(512, 2) void joint8_kernel(
    const char* __restrict__ himg,
    const char* __restrict__ wimg,
    const float* __restrict__ b2,
    float* __restrict__ out) {
    __shared__ __align__(16) char lds[131072];

    // bijective XCD swizzle (1600 % 8 == 0): each XCD gets 200 consecutive
    // work items; nt fastest so the 4 N-tiles of an M-tile share L2.
    const int bid = blockIdx.x;
    const int swz = (bid & 7) * (MT_ * NT_ / 8) + (bid >> 3);
    const int mt = swz >> 2;
    const int nt = swz & 3;
    const int m0 = mt * 256;
    const int n0 = nt * 256;

    const int tid  = threadIdx.x;
    const int wid  = tid >> 6;
    const int lane = tid & 63;
    const int wm   = (wid & 4) ? 128 : 0;   // wave row block (2M)
    const int wn   = (wid & 3) * 64;        // wave col block (4N)
    const int fr   = lane & 15;
    const int q16  = lane >> 4;             // 0..3, selects 8-elem k slice

    f32x4 acc[8][4] = {};                    // [row frag][col frag]
    short8 fa0[4][2], fa1[4][2], fb0[2][2], fb1[2][2];

    // stage one 16-KB region: 2 x gload_lds16 per thread (uniform count).
    auto stage = [&](int rho) {
        const int t  = rho >> 2;
        const int rr = rho & 3;              // 0:RA0 1:RB0 2:RB1 3:RA1
        char* slot = lds + ((t & 1) << 16);
        if (rr == 0 || rr == 3) {
            const char* blk = himg + (((size_t)(t * MT_ + mt)) << 15);
            const int ra = (rr == 3);
            #pragma unroll
            for (int j = 0; j < 2; ++j) {
                const int off = ra * 8192 + j * 16384 + wid * 1024;
                gload_lds16(blk + off + lane * 16, slot + off);
            }
        } else {
            const char* blk = wimg + (((size_t)(t * NT_ + nt)) << 15);
            const int rb = (rr == 2);
            char* bslot = slot + 32768;
            #pragma unroll
            for (int j = 0; j < 2; ++j) {
                const int off = j * 16384 + (wid >> 2) * 8192 + rb * 4096 + (wid & 3) * 1024;
                gload_lds16(blk + off + lane * 16, bslot + off);
            }
        }
    };

    // prologue: regions 0..4 (tile0 complete + tile1.RA0) = 10 loads in flight
    stage(0); stage(1); stage(2); stage(3); stage(4);

    #pragma unroll
    for (int g = 0; g < 32; ++g) {
        const int t = g >> 2;
        const int c = g & 3;
        if (g <= 27)      asm volatile("s_waitcnt vmcnt(6)" ::: "memory");
        else if (g == 28) asm volatile("s_waitcnt vmcnt(4)" ::: "memory");
        else if (g == 29) asm volatile("s_waitcnt vmcnt(2)" ::: "memory");
        else              asm volatile("s_waitcnt vmcnt(0)" ::: "memory");
        __builtin_amdgcn_s_barrier();
        if (g + 5 < 32) stage(g + 5);

        const char* Asl = lds + ((t & 1) << 16);
        const char* Bsl = Asl + 32768;

        if (c == 0) {                       // quad (qm0,qn0): read fa0, fb0
            #pragma unroll
            for (int i = 0; i < 4; ++i) {
                const int R = wm + i * 16 + fr;
                const int sw = (R & 7) << 4;
                fa0[i][0] = *(const short8*)(Asl + R * 128 + ((q16 * 16) ^ sw));
                fa0[i][1] = *(const short8*)(Asl + R * 128 + ((64 + q16 * 16) ^ sw));
            }
            #pragma unroll
            for (int j = 0; j < 2; ++j) {
                const int R = wn + j * 16 + fr;
                const int sw = (R & 7) << 4;
                fb0[j][0] = *(const short8*)(Bsl + R * 128 + ((q16 * 16) ^ sw));
                fb0[j][1] = *(const short8*)(Bsl + R * 128 + ((64 + q16 * 16) ^ sw));
            }
            __builtin_amdgcn_s_setprio(1);
            #pragma unroll
            for (int i = 0; i < 4; ++i)
                #pragma unroll
                for (int j = 0; j < 2; ++j) {
                    acc[i][j] = __builtin_amdgcn_mfma_f32_16x16x32_bf16(
                        fa0[i][0], fb0[j][0], acc[i][j], 0, 0, 0);
                    acc[i][j] = __builtin_amdgcn_mfma_f32_16x16x32_bf16(
                        fa0[i][1], fb0[j][1], acc[i][j], 0, 0, 0);
                }
            __builtin_amdgcn_s_setprio(0);
        } else if (c == 1) {                // quad (qm0,qn1): read fb1
            #pragma unroll
            for (int j = 0; j < 2; ++j) {
                const int R = wn + 32 + j * 16 + fr;
                const int sw = (R & 7) << 4;
                fb1[j][0] = *(const short8*)(Bsl + R * 128 + ((q16 * 16) ^ sw));
                fb1[j][1] = *(const short8*)(Bsl + R * 128 + ((64 + q16 * 16) ^ sw));
            }
            __builtin_amdgcn_s_setprio(1);
            #pragma unroll
            for (int i = 0; i < 4; ++i)
                #pragma unroll
                for (int j = 0; j < 2; ++j) {
                    acc[i][2 + j] = __builtin_amdgcn_mfma_f32_16x16x32_bf16(
                        fa0[i][0], fb1[j][0], acc[i][2 + j], 0, 0, 0);
                    acc[i][2 + j] = __builtin_amdgcn_mfma_f32_16x16x32_bf16(
                        fa0[i][1], fb1[j][1], acc[i][2 + j], 0, 0, 0);
                }
            __builtin_amdgcn_s_setprio(0);
        } else if (c == 2) {                // quad (qm1,qn1): read fa1
            #pragma unroll
            for (int i = 0; i < 4; ++i) {
                const int R = wm + 64 + i * 16 + fr;
                const int sw = (R & 7) << 4;
                fa1[i][0] = *(const short8*)(Asl + R * 128 + ((q16 * 16) ^ sw));
                fa1[i][1] = *(const short8*)(Asl + R * 128 + ((64 + q16 * 16) ^ sw));
            }
            __builtin_amdgcn_s_setprio(1);
            #pragma unroll
            for (int i = 0; i < 4; ++i)
                #pragma unroll
                for (int j = 0; j < 2; ++j) {
                    acc[4 + i][2 + j] = __builtin_amdgcn_mfma_f32_16x16x32_bf16(
                        fa1[i][0], fb1[j][0], acc[4 + i][2 + j], 0, 0, 0);
                    acc[4 + i][2 + j] = __builtin_amdgcn_mfma_f32_16x16x32_bf16(
                        fa1[i][1], fb1[j][1], acc[4 + i][2 + j], 0, 0, 0);
                }
            __builtin_amdgcn_s_setprio(0);
        } else {                            // quad (qm1,qn0): pure-register
            __builtin_amdgcn_s_setprio(1);
            #pragma unroll
            for (int i = 0; i < 4; ++i)
                #pragma unroll
                for (int j = 0; j < 2; ++j) {
                    acc[4 + i][j] = __builtin_amdgcn_mfma_f32_16x16x32_bf16(
                        fa1[i][0], fb0[j][0], acc[4 + i][j], 0, 0, 0);
                    acc[4 + i][j] = __builtin_amdgcn_mfma_f32_16x16x32_bf16(
                        fa1[i][1], fb0[j][1], acc[4 + i][j], 0, 0, 0);
                }
            __builtin_amdgcn_s_setprio(0);
        }
    }

    // ---- epilogue: + b2, fp32 store. 16x16 C layout: col=lane&15,
    // row=(lane>>4)*4+reg (m89-verified) ----
    const int rq = q16 * 4;
    const int cl = fr;
    #pragma unroll
    for (int cj = 0; cj < 4; ++cj) {
        const int col = n0 + wn + (cj >> 1) * 32 + (cj & 1) * 16 + cl;
        const float bias = b2[col];
        #pragma unroll
        for (int ri = 0; ri < 8; ++ri) {
            const size_t rbase = (size_t)(m0 + wm + (ri >> 2) * 64 + (ri & 3) * 16 + rq);
            #pragma unroll
            for (int r = 0; r < 4; ++r)
                out[(rbase + r) * VOCAB_ + col] = acc[ri][cj][r] + bias;
        }
    }
}

extern "C" void kernel_launch(void* const* d_in, const int* in_sizes, int n_in,
                              void* d_out, int out_size, void* d_ws, size_t ws_size,
                              hipStream_t stream) {
    const float* enc = (const float*)d_in[0];
    const float* dec = (const float*)d_in[1];
    const float* W1  = (const float*)d_in[2];
    const float* b1  = (const float*)d_in[3];
    const float* W2  = (const float*)d_in[4];
    const float* b2  = (const float*)d_in[5];
    float* out = (float*)d_out;

    const size_t PROJ_BYTES = (size_t)NROWS_ * INNER_ * sizeof(float);  // 3,801,088
    const size_t W2_BYTES   = (size_t)VOCAB_ * INNER_ * 2;              // 1 MiB

    float* proj = (float*)d_ws;
    float* encp = proj;
    float* decp = proj + (size_t)BT_ * INNER_;
    char*  w2t  = (char*)d_ws + PROJ_BYTES;
    char*  hbf  = w2t + W2_BYTES;

    prep_kernel<<<PROJ_BLOCKS + CVT_BLOCKS, 256, 0, stream>>>(
        enc, dec, W1, b1, W2, proj, w2t);
    hgen_kernel<<<(M_ * INNER_) / (8 * 256), 256, 0, stream>>>(encp, decp, hbf);
    joint8_kernel<<<MT_ * NT_, 512, 0, stream>>>(hbf, w2t, b2, out);
}